// Round 5
// baseline (502.195 us; speedup 1.0000x reference)
//
#include <hip/hip_runtime.h>

#define N 100000
#define E 1000000
#define ETOT 1100000   // E + N self-loops
#define NB1 391        // ceil(N/256)

typedef __attribute__((ext_vector_type(8))) short bf16x8;
typedef __attribute__((ext_vector_type(4))) float f32x4;

__device__ __forceinline__ float lrelu(float x) { return x > 0.f ? x : 0.2f * x; }
// f32 -> bf16 bits, round-to-nearest-even
__device__ __forceinline__ unsigned short f2b(float x) {
    unsigned u = __float_as_uint(x);
    return (unsigned short)((u + 0x7FFFu + ((u >> 16) & 1u)) >> 16);
}
__device__ __forceinline__ float b2f(unsigned short v) {
    return __uint_as_float(((unsigned)v) << 16);
}

// ---------------- CSR build ----------------
__global__ __launch_bounds__(256) void hist_kernel(const int* __restrict__ ei,
                                                   int* __restrict__ hist) {
    const int e = blockIdx.x * 256 + threadIdx.x;
    if (e >= ETOT) return;
    int d = (e < E) ? ei[E + e] : (e - E);
    atomicAdd(&hist[d], 1);
}

__global__ __launch_bounds__(256) void scan1_kernel(const int* __restrict__ hist,
                                                    int* __restrict__ rofs,
                                                    int* __restrict__ bsum) {
    __shared__ int sm[256];
    const int t = threadIdx.x;
    const int i = blockIdx.x * 256 + t;
    int v = (i < N) ? hist[i] : 0;
    sm[t] = v;
    __syncthreads();
#pragma unroll
    for (int off = 1; off < 256; off <<= 1) {
        int x = (t >= off) ? sm[t - off] : 0;
        __syncthreads();
        sm[t] += x;
        __syncthreads();
    }
    if (i < N) rofs[i] = sm[t] - v;
    if (t == 255) bsum[blockIdx.x] = sm[255];
}

__global__ __launch_bounds__(512) void scan2_kernel(int* __restrict__ bsum) {
    __shared__ int sm[512];
    const int t = threadIdx.x;
    int v = (t < NB1) ? bsum[t] : 0;
    sm[t] = v;
    __syncthreads();
#pragma unroll
    for (int off = 1; off < 512; off <<= 1) {
        int x = (t >= off) ? sm[t - off] : 0;
        __syncthreads();
        sm[t] += x;
        __syncthreads();
    }
    if (t < NB1) bsum[t] = sm[t] - v;
}

__global__ __launch_bounds__(256) void scan3_kernel(int* __restrict__ rofs,
                                                    const int* __restrict__ bsum,
                                                    int* __restrict__ cursor) {
    const int i = blockIdx.x * 256 + threadIdx.x;
    if (i < N) {
        int r = rofs[i] + bsum[blockIdx.x];
        rofs[i] = r;
        cursor[i] = r;
    }
    if (i == 0) rofs[N] = ETOT;
}

__global__ __launch_bounds__(256) void scatter_kernel(const int* __restrict__ ei,
                                                      int* __restrict__ cursor,
                                                      int* __restrict__ esrc) {
    const int e = blockIdx.x * 256 + threadIdx.x;
    if (e >= ETOT) return;
    int s, d;
    if (e < E) { s = ei[e]; d = ei[E + e]; } else { s = d = e - E; }
    int pos = atomicAdd(&cursor[d], 1);
    esrc[pos] = s;
}

// ---------------- weight transposes (bf16), merged ----------------
__global__ __launch_bounds__(256) void wt_kernel(const float* __restrict__ W1,
                                                 const float* __restrict__ W2,
                                                 unsigned short* __restrict__ W1T,
                                                 unsigned short* __restrict__ W2T) {
    const int b = blockIdx.x;
    const int t = threadIdx.x;
    if (b < 128) {
        // W1T[n][k] = W1[k][n], k=b, n=t
        W1T[(size_t)t * 128 + b] = f2b(W1[(size_t)b * 256 + t]);
    } else {
        // W2T[n][k] = W2[k][n], n=b-128, k=t
        int n = b - 128;
        W2T[(size_t)n * 256 + t] = f2b(W2[(size_t)t * 32 + n]);
    }
}

// ---------------- layer 1 GEMM via MFMA bf16: h1 = x0 @ W1, h1 stored bf16 ----------------
__global__ __launch_bounds__(256) void gemm1_kernel(const float* __restrict__ x0,
                                                    const unsigned short* __restrict__ W1T,
                                                    unsigned short* __restrict__ h1) {
    const int wv = threadIdx.x >> 6;
    const int lane = threadIdx.x & 63;
    const int quad = lane >> 4, c = lane & 15;
    const int base_m = blockIdx.x * 128 + wv * 32;
    bf16x8 af[2][4];
#pragma unroll
    for (int mt = 0; mt < 2; mt++) {
        int row = base_m + mt * 16 + c;
        int rowc = row < N ? row : N - 1;
        const float* ap = x0 + (size_t)rowc * 128 + quad * 8;
#pragma unroll
        for (int ks = 0; ks < 4; ks++) {
            float4 lo = *(const float4*)(ap + ks * 32);
            float4 hi = *(const float4*)(ap + ks * 32 + 4);
            bf16x8 f;
            f[0] = (short)f2b(lo.x); f[1] = (short)f2b(lo.y);
            f[2] = (short)f2b(lo.z); f[3] = (short)f2b(lo.w);
            f[4] = (short)f2b(hi.x); f[5] = (short)f2b(hi.y);
            f[6] = (short)f2b(hi.z); f[7] = (short)f2b(hi.w);
            af[mt][ks] = f;
        }
    }
    for (int nt = 0; nt < 16; nt++) {
        f32x4 acc0 = {0.f, 0.f, 0.f, 0.f};
        f32x4 acc1 = {0.f, 0.f, 0.f, 0.f};
#pragma unroll
        for (int ks = 0; ks < 4; ks++) {
            bf16x8 bf = *(const bf16x8*)(W1T + (size_t)(nt * 16 + c) * 128 + ks * 32 + quad * 8);
            acc0 = __builtin_amdgcn_mfma_f32_16x16x32_bf16(af[0][ks], bf, acc0, 0, 0, 0);
            acc1 = __builtin_amdgcn_mfma_f32_16x16x32_bf16(af[1][ks], bf, acc1, 0, 0, 0);
        }
        const int col = nt * 16 + c;
#pragma unroll
        for (int r = 0; r < 4; r++) {
            int row0 = base_m + quad * 4 + r;
            if (row0 < N) h1[(size_t)row0 * 256 + col] = f2b(acc0[r]);
            int row1 = base_m + 16 + quad * 4 + r;
            if (row1 < N) h1[(size_t)row1 * 256 + col] = f2b(acc1[r]);
        }
    }
}

// ---------------- attention logits: a_src1/a_dst1 [N,8] from bf16 h1 ----------------
__global__ __launch_bounds__(256) void att1_kernel(const unsigned short* __restrict__ h1,
                                                   const float* __restrict__ att_src,
                                                   const float* __restrict__ att_dst,
                                                   float* __restrict__ a_src,
                                                   float* __restrict__ a_dst) {
    const int wid = (blockIdx.x * 256 + threadIdx.x) >> 6;
    const int lane = threadIdx.x & 63;
    ushort4 hb = ((const ushort4*)(h1 + (size_t)wid * 256))[lane];
    float4 hv = {b2f(hb.x), b2f(hb.y), b2f(hb.z), b2f(hb.w)};
    float4 as = ((const float4*)att_src)[lane];
    float4 ad = ((const float4*)att_dst)[lane];
    float ps = hv.x * as.x + hv.y * as.y + hv.z * as.z + hv.w * as.w;
    float pd = hv.x * ad.x + hv.y * ad.y + hv.z * ad.z + hv.w * ad.w;
#pragma unroll
    for (int off = 1; off < 8; off <<= 1) {
        ps += __shfl_xor(ps, off, 64);
        pd += __shfl_xor(pd, off, 64);
    }
    if ((lane & 7) == 0) {
        int h = lane >> 3;
        a_src[wid * 8 + h] = ps;
        a_dst[wid * 8 + h] = pd;
    }
}

// ---------------- layer 1 edge weights: exact two-pass softmax, all exps here ----------------
// wave per node; lane = (edge-slot e8 = lane>>3, head h = lane&7)
__global__ __launch_bounds__(256) void alpha1_kernel(const int* __restrict__ esrc,
                                                     const int* __restrict__ rofs,
                                                     const float* __restrict__ a_src,
                                                     const float* __restrict__ a_dst,
                                                     float* __restrict__ ew,
                                                     float* __restrict__ iden) {
    const int n = (blockIdx.x * 256 + threadIdx.x) >> 6;
    const int lane = threadIdx.x & 63;
    const int e8 = lane >> 3, h = lane & 7;
    if (n >= N) return;
    const int rs = rofs[n], re = rofs[n + 1];
    const float ad = a_dst[(size_t)n * 8 + h];
    // pass 1: per-head max of a_src over incoming edges (lrelu is monotone)
    float M = -1e30f;
    for (int j = rs + e8; j < re; j += 8) M = fmaxf(M, a_src[(size_t)esrc[j] * 8 + h]);
    M = fmaxf(M, __shfl_xor(M, 8, 64));
    M = fmaxf(M, __shfl_xor(M, 16, 64));
    M = fmaxf(M, __shfl_xor(M, 32, 64));
    const float Mh = lrelu(M + ad);
    // pass 2: ew = exp(alpha - Mh); den accumulate
    float den = 0.f;
    for (int j = rs + e8; j < re; j += 8) {
        float w = __expf(lrelu(a_src[(size_t)esrc[j] * 8 + h] + ad) - Mh);
        ew[(size_t)j * 8 + h] = w;
        den += w;
    }
    den += __shfl_xor(den, 8, 64);
    den += __shfl_xor(den, 16, 64);
    den += __shfl_xor(den, 32, 64);
    if (lane < 8) iden[(size_t)n * 8 + h] = 1.0f / den;
}

// ---------------- layer 1 weighted aggregate: one wave per node, 4 fmac chains ----------------
__global__ __launch_bounds__(256) void seg1_kernel(const int* __restrict__ esrc,
                                                   const int* __restrict__ rofs,
                                                   const float* __restrict__ ew,
                                                   const float* __restrict__ iden,
                                                   const unsigned short* __restrict__ h1,
                                                   const float* __restrict__ b1,
                                                   unsigned short* __restrict__ x2) {
    const int n = (blockIdx.x * 256 + threadIdx.x) >> 6;
    const int lane = threadIdx.x & 63;
    const int h = lane >> 3;
    if (n >= N) return;
    const int rs = rofs[n], re = rofs[n + 1];
    float4 A0 = {0, 0, 0, 0}, A1 = {0, 0, 0, 0}, A2 = {0, 0, 0, 0}, A3 = {0, 0, 0, 0};
    int j = rs;
    for (; j + 4 <= re; j += 4) {
        int s0 = esrc[j], s1 = esrc[j + 1], s2 = esrc[j + 2], s3 = esrc[j + 3];
        float w0 = ew[(size_t)(j + 0) * 8 + h];
        float w1 = ew[(size_t)(j + 1) * 8 + h];
        float w2 = ew[(size_t)(j + 2) * 8 + h];
        float w3 = ew[(size_t)(j + 3) * 8 + h];
        ushort4 hb0 = ((const ushort4*)(h1 + (size_t)s0 * 256))[lane];
        ushort4 hb1 = ((const ushort4*)(h1 + (size_t)s1 * 256))[lane];
        ushort4 hb2 = ((const ushort4*)(h1 + (size_t)s2 * 256))[lane];
        ushort4 hb3 = ((const ushort4*)(h1 + (size_t)s3 * 256))[lane];
        A0.x += w0 * b2f(hb0.x); A0.y += w0 * b2f(hb0.y); A0.z += w0 * b2f(hb0.z); A0.w += w0 * b2f(hb0.w);
        A1.x += w1 * b2f(hb1.x); A1.y += w1 * b2f(hb1.y); A1.z += w1 * b2f(hb1.z); A1.w += w1 * b2f(hb1.w);
        A2.x += w2 * b2f(hb2.x); A2.y += w2 * b2f(hb2.y); A2.z += w2 * b2f(hb2.z); A2.w += w2 * b2f(hb2.w);
        A3.x += w3 * b2f(hb3.x); A3.y += w3 * b2f(hb3.y); A3.z += w3 * b2f(hb3.z); A3.w += w3 * b2f(hb3.w);
    }
    for (; j < re; j++) {
        int s0 = esrc[j];
        float w0 = ew[(size_t)j * 8 + h];
        ushort4 hb0 = ((const ushort4*)(h1 + (size_t)s0 * 256))[lane];
        A0.x += w0 * b2f(hb0.x); A0.y += w0 * b2f(hb0.y); A0.z += w0 * b2f(hb0.z); A0.w += w0 * b2f(hb0.w);
    }
    float4 acc;
    acc.x = (A0.x + A1.x) + (A2.x + A3.x);
    acc.y = (A0.y + A1.y) + (A2.y + A3.y);
    acc.z = (A0.z + A1.z) + (A2.z + A3.z);
    acc.w = (A0.w + A1.w) + (A2.w + A3.w);
    const float inv = iden[(size_t)n * 8 + h];
    float4 bb = ((const float4*)b1)[lane];
    float vx = acc.x * inv + bb.x, vy = acc.y * inv + bb.y;
    float vz = acc.z * inv + bb.z, vw = acc.w * inv + bb.w;
    vx = vx > 0.f ? vx : 0.f; vy = vy > 0.f ? vy : 0.f;
    vz = vz > 0.f ? vz : 0.f; vw = vw > 0.f ? vw : 0.f;
    ushort4 o = {f2b(vx), f2b(vy), f2b(vz), f2b(vw)};
    ((ushort4*)(x2 + (size_t)n * 256))[lane] = o;
}

// ---------------- layer 2 GEMM via MFMA: h2 = x2 @ W2 (256->32), fused logits ----------------
__global__ __launch_bounds__(256) void gemm2_kernel(const unsigned short* __restrict__ x2,
                                                    const unsigned short* __restrict__ W2T,
                                                    const float* __restrict__ att_src2,
                                                    const float* __restrict__ att_dst2,
                                                    unsigned short* __restrict__ h2,
                                                    float* __restrict__ a_src2,
                                                    float* __restrict__ a_dst2) {
    const int wv = threadIdx.x >> 6;
    const int lane = threadIdx.x & 63;
    const int quad = lane >> 4, c = lane & 15;
    const int base_m = blockIdx.x * 128 + wv * 32;
    f32x4 acc[2][2] = {{{0, 0, 0, 0}, {0, 0, 0, 0}}, {{0, 0, 0, 0}, {0, 0, 0, 0}}};
#pragma unroll
    for (int ks = 0; ks < 8; ks++) {
        bf16x8 b0 = *(const bf16x8*)(W2T + (size_t)c * 256 + ks * 32 + quad * 8);
        bf16x8 b1 = *(const bf16x8*)(W2T + (size_t)(16 + c) * 256 + ks * 32 + quad * 8);
#pragma unroll
        for (int mt = 0; mt < 2; mt++) {
            int row = base_m + mt * 16 + c;
            int rowc = row < N ? row : N - 1;
            bf16x8 a = *(const bf16x8*)(x2 + (size_t)rowc * 256 + ks * 32 + quad * 8);
            acc[mt][0] = __builtin_amdgcn_mfma_f32_16x16x32_bf16(a, b0, acc[mt][0], 0, 0, 0);
            acc[mt][1] = __builtin_amdgcn_mfma_f32_16x16x32_bf16(a, b1, acc[mt][1], 0, 0, 0);
        }
    }
    float as0 = att_src2[c], as1 = att_src2[16 + c];
    float ad0 = att_dst2[c], ad1 = att_dst2[16 + c];
#pragma unroll
    for (int mt = 0; mt < 2; mt++) {
#pragma unroll
        for (int r = 0; r < 4; r++) {
            int row = base_m + mt * 16 + quad * 4 + r;
            float v0 = acc[mt][0][r], v1 = acc[mt][1][r];
            float ps = v0 * as0 + v1 * as1;
            float pd = v0 * ad0 + v1 * ad1;
#pragma unroll
            for (int off = 1; off < 16; off <<= 1) {
                ps += __shfl_xor(ps, off, 64);
                pd += __shfl_xor(pd, off, 64);
            }
            if (row < N) {
                h2[(size_t)row * 32 + c] = f2b(v0);
                h2[(size_t)row * 32 + 16 + c] = f2b(v1);
                if (c == 0) { a_src2[row] = ps; a_dst2[row] = pd; }
            }
        }
    }
}

// ---------------- layer 2 edge weights: 16 lanes per node ----------------
__global__ __launch_bounds__(256) void alpha2_kernel(const int* __restrict__ esrc,
                                                     const int* __restrict__ rofs,
                                                     const float* __restrict__ a_src2,
                                                     const float* __restrict__ a_dst2,
                                                     float* __restrict__ ew2,
                                                     float* __restrict__ iden2) {
    const int n = (blockIdx.x * 256 + threadIdx.x) >> 4;
    const int le = threadIdx.x & 15;
    if (n >= N) return;
    const int rs = rofs[n], re = rofs[n + 1];
    const float ad = a_dst2[n];
    float M = -1e30f;
    for (int j = rs + le; j < re; j += 16) M = fmaxf(M, a_src2[esrc[j]]);
    M = fmaxf(M, __shfl_xor(M, 1, 64));
    M = fmaxf(M, __shfl_xor(M, 2, 64));
    M = fmaxf(M, __shfl_xor(M, 4, 64));
    M = fmaxf(M, __shfl_xor(M, 8, 64));
    const float Mh = lrelu(M + ad);
    float den = 0.f;
    for (int j = rs + le; j < re; j += 16) {
        float w = __expf(lrelu(a_src2[esrc[j]] + ad) - Mh);
        ew2[j] = w;
        den += w;
    }
    den += __shfl_xor(den, 1, 64);
    den += __shfl_xor(den, 2, 64);
    den += __shfl_xor(den, 4, 64);
    den += __shfl_xor(den, 8, 64);
    if (le == 0) iden2[n] = 1.0f / den;
}

// ---------------- layer 2 weighted aggregate: half-wave per node, 4 chains ----------------
__global__ __launch_bounds__(256) void seg2_kernel(const int* __restrict__ esrc,
                                                   const int* __restrict__ rofs,
                                                   const float* __restrict__ ew2,
                                                   const float* __restrict__ iden2,
                                                   const unsigned short* __restrict__ h2,
                                                   const float* __restrict__ b2,
                                                   float* __restrict__ v2) {
    const int n = (blockIdx.x * 256 + threadIdx.x) >> 5;
    const int c = threadIdx.x & 31;
    if (n >= N) return;
    const int rs = rofs[n], re = rofs[n + 1];
    float A0 = 0.f, A1 = 0.f, A2 = 0.f, A3 = 0.f;
    int j = rs;
    for (; j + 4 <= re; j += 4) {
        int s0 = esrc[j], s1 = esrc[j + 1], s2 = esrc[j + 2], s3 = esrc[j + 3];
        float w0 = ew2[j], w1 = ew2[j + 1], w2 = ew2[j + 2], w3 = ew2[j + 3];
        A0 += w0 * b2f(h2[(size_t)s0 * 32 + c]);
        A1 += w1 * b2f(h2[(size_t)s1 * 32 + c]);
        A2 += w2 * b2f(h2[(size_t)s2 * 32 + c]);
        A3 += w3 * b2f(h2[(size_t)s3 * 32 + c]);
    }
    for (; j < re; j++) {
        A0 += ew2[j] * b2f(h2[(size_t)esrc[j] * 32 + c]);
    }
    float acc = (A0 + A1) + (A2 + A3);
    v2[(size_t)n * 32 + c] = acc * iden2[n] + b2[c];
}

// ---------------- final: linear 32->40 ----------------
__global__ __launch_bounds__(256) void final_kernel(const float* __restrict__ v2,
                                                    const float* __restrict__ linW,
                                                    const float* __restrict__ linb,
                                                    float* __restrict__ out) {
    __shared__ float lws[32 * 40];
    __shared__ float vbuf[4][32];
    const int t = threadIdx.x;
    for (int i = t; i < 1280; i += 256) lws[i] = linW[i];
    const int w = t >> 6, lane = t & 63;
    const int n = blockIdx.x * 4 + w;
    if (lane < 32) vbuf[w][lane] = v2[(size_t)n * 32 + lane];
    __syncthreads();
    if (lane < 40) {
        float acc = linb[lane];
#pragma unroll
        for (int c = 0; c < 32; c++) acc += vbuf[w][c] * lws[c * 40 + lane];
        out[(size_t)n * 40 + lane] = acc;
    }
}

extern "C" void kernel_launch(void* const* d_in, const int* in_sizes, int n_in,
                              void* d_out, int out_size, void* d_ws, size_t ws_size,
                              hipStream_t stream) {
    const float* x0       = (const float*)d_in[0];
    const float* W1       = (const float*)d_in[1];
    const float* att_src1 = (const float*)d_in[2];
    const float* att_dst1 = (const float*)d_in[3];
    const float* b1       = (const float*)d_in[4];
    const float* W2       = (const float*)d_in[5];
    const float* att_src2 = (const float*)d_in[6];
    const float* att_dst2 = (const float*)d_in[7];
    const float* b2       = (const float*)d_in[8];
    const float* linW     = (const float*)d_in[9];
    const float* linb     = (const float*)d_in[10];
    const int*   ei       = (const int*)d_in[11];
    float* out = (float*)d_out;
    float* ws  = (float*)d_ws;

    unsigned short* h1  = (unsigned short*)ws;                  // 25.6M bf16
    unsigned short* x2  = (unsigned short*)(ws + 12800000);     // 25.6M bf16
    float* a_src1       = ws + 25600000;                        // 0.8M
    float* a_dst1       = ws + 26400000;                        // 0.8M
    unsigned short* h2  = (unsigned short*)(ws + 27200000);     // 3.2M bf16
    float* v2           = ws + 28800000;                        // 3.2M
    float* a_src2       = ws + 32000000;                        // 0.1M
    float* a_dst2       = ws + 32100000;                        // 0.1M
    unsigned short* W1T = (unsigned short*)(ws + 32200000);     // 32768 bf16
    unsigned short* W2T = (unsigned short*)(ws + 32220000);     // 8192 bf16
    int*   hist         = (int*)(ws + 32230000);                // 0.1M
    int*   rofs         = (int*)(ws + 32330000);                // N+1
    int*   cursor       = (int*)(ws + 32440000);                // 0.1M
    int*   bsum         = (int*)(ws + 32540000);                // 512
    int*   esrc         = (int*)(ws + 32541000);                // 1.1M
    float* ew1          = ws + 33700000;                        // 8.8M (ETOT*8)
    float* iden1        = ws + 42500000;                        // 0.8M
    float* ew2          = ws + 43300000;                        // 1.1M
    float* iden2        = ws + 44400000;                        // 0.1M

    hipMemsetAsync(hist, 0, (size_t)N * 4, stream);

    hist_kernel<<<(ETOT + 255) / 256, 256, 0, stream>>>(ei, hist);
    scan1_kernel<<<NB1, 256, 0, stream>>>(hist, rofs, bsum);
    scan2_kernel<<<1, 512, 0, stream>>>(bsum);
    scan3_kernel<<<NB1, 256, 0, stream>>>(rofs, bsum, cursor);
    scatter_kernel<<<(ETOT + 255) / 256, 256, 0, stream>>>(ei, cursor, esrc);

    wt_kernel<<<160, 256, 0, stream>>>(W1, W2, W1T, W2T);
    gemm1_kernel<<<(N + 127) / 128, 256, 0, stream>>>(x0, W1T, h1);
    att1_kernel<<<N / 4, 256, 0, stream>>>(h1, att_src1, att_dst1, a_src1, a_dst1);
    alpha1_kernel<<<N / 4, 256, 0, stream>>>(esrc, rofs, a_src1, a_dst1, ew1, iden1);
    seg1_kernel<<<N / 4, 256, 0, stream>>>(esrc, rofs, ew1, iden1, h1, b1, x2);
    gemm2_kernel<<<(N + 127) / 128, 256, 0, stream>>>(x2, W2T, att_src2, att_dst2, h2, a_src2, a_dst2);
    alpha2_kernel<<<N / 16, 256, 0, stream>>>(esrc, rofs, a_src2, a_dst2, ew2, iden2);
    seg2_kernel<<<N / 8, 256, 0, stream>>>(esrc, rofs, ew2, iden2, h2, b2, v2);
    final_kernel<<<N / 4, 256, 0, stream>>>(v2, linW, linb, out);
}

// Round 6
// 452.760 us; speedup vs baseline: 1.1092x; 1.1092x over previous
//
#include <hip/hip_runtime.h>

#define N 100000
#define E 1000000
#define ETOT 1100000   // E + N self-loops
#define NB1 391        // ceil(N/256)

typedef __attribute__((ext_vector_type(8))) short bf16x8;
typedef __attribute__((ext_vector_type(4))) float f32x4;

__device__ __forceinline__ float lrelu(float x) { return x > 0.f ? x : 0.2f * x; }
// f32 -> bf16 bits, round-to-nearest-even
__device__ __forceinline__ unsigned short f2b(float x) {
    unsigned u = __float_as_uint(x);
    return (unsigned short)((u + 0x7FFFu + ((u >> 16) & 1u)) >> 16);
}
__device__ __forceinline__ float b2f(unsigned short v) {
    return __uint_as_float(((unsigned)v) << 16);
}

// ---------------- CSR build ----------------
__global__ __launch_bounds__(256) void hist_kernel(const int* __restrict__ ei,
                                                   int* __restrict__ hist) {
    const int e = blockIdx.x * 256 + threadIdx.x;
    if (e >= ETOT) return;
    int d = (e < E) ? ei[E + e] : (e - E);
    atomicAdd(&hist[d], 1);
}

__global__ __launch_bounds__(256) void scan1_kernel(const int* __restrict__ hist,
                                                    int* __restrict__ rofs,
                                                    int* __restrict__ bsum) {
    __shared__ int sm[256];
    const int t = threadIdx.x;
    const int i = blockIdx.x * 256 + t;
    int v = (i < N) ? hist[i] : 0;
    sm[t] = v;
    __syncthreads();
#pragma unroll
    for (int off = 1; off < 256; off <<= 1) {
        int x = (t >= off) ? sm[t - off] : 0;
        __syncthreads();
        sm[t] += x;
        __syncthreads();
    }
    if (i < N) rofs[i] = sm[t] - v;
    if (t == 255) bsum[blockIdx.x] = sm[255];
}

__global__ __launch_bounds__(512) void scan2_kernel(int* __restrict__ bsum) {
    __shared__ int sm[512];
    const int t = threadIdx.x;
    int v = (t < NB1) ? bsum[t] : 0;
    sm[t] = v;
    __syncthreads();
#pragma unroll
    for (int off = 1; off < 512; off <<= 1) {
        int x = (t >= off) ? sm[t - off] : 0;
        __syncthreads();
        sm[t] += x;
        __syncthreads();
    }
    if (t < NB1) bsum[t] = sm[t] - v;
}

__global__ __launch_bounds__(256) void scan3_kernel(int* __restrict__ rofs,
                                                    const int* __restrict__ bsum,
                                                    int* __restrict__ cursor) {
    const int i = blockIdx.x * 256 + threadIdx.x;
    if (i < N) {
        int r = rofs[i] + bsum[blockIdx.x];
        rofs[i] = r;
        cursor[i] = r;
    }
    if (i == 0) rofs[N] = ETOT;
}

__global__ __launch_bounds__(256) void scatter_kernel(const int* __restrict__ ei,
                                                      int* __restrict__ cursor,
                                                      int* __restrict__ esrc) {
    const int e = blockIdx.x * 256 + threadIdx.x;
    if (e >= ETOT) return;
    int s, d;
    if (e < E) { s = ei[e]; d = ei[E + e]; } else { s = d = e - E; }
    int pos = atomicAdd(&cursor[d], 1);
    esrc[pos] = s;
}

// ---------------- weight prep (bf16): W1T rows 0..255, logit-fold rows 256..271, W2T ----------------
// W1T layout: [272][128].  Row n<256: W1T[n][k] = W1[k][n].
// Row 256+c (c<8):  src-fold head c:  Wsa[k] = sum_{j<32} W1[k][c*32+j]*att_src1[c*32+j]
// Row 264+c (c<8):  dst-fold head c.
__global__ __launch_bounds__(256) void wt_kernel(const float* __restrict__ W1,
                                                 const float* __restrict__ W2,
                                                 const float* __restrict__ att_src1,
                                                 const float* __restrict__ att_dst1,
                                                 unsigned short* __restrict__ W1T,
                                                 unsigned short* __restrict__ W2T) {
    const int b = blockIdx.x;
    const int t = threadIdx.x;
    if (b < 128) {
        W1T[(size_t)t * 128 + b] = f2b(W1[(size_t)b * 256 + t]);
    } else if (b < 160) {
        int n = b - 128;
        W2T[(size_t)n * 256 + t] = f2b(W2[(size_t)t * 32 + n]);
    } else {
        // fold tile: idx over 16 cols x 128 k
        int idx = (b - 160) * 256 + t;          // 0..2047
        int col = idx >> 7;                     // 0..15
        int k = idx & 127;
        int h = col & 7;
        const float* att = (col < 8) ? att_src1 : att_dst1;
        float acc = 0.f;
#pragma unroll 8
        for (int j = 0; j < 32; j++) acc += W1[(size_t)k * 256 + h * 32 + j] * att[h * 32 + j];
        W1T[(size_t)(256 + col) * 128 + k] = f2b(acc);
    }
}

// ---------------- layer 1 GEMM via MFMA bf16: h1 = x0 @ W1 (+ fused logits) ----------------
__global__ __launch_bounds__(256) void gemm1_kernel(const float* __restrict__ x0,
                                                    const unsigned short* __restrict__ W1T,
                                                    unsigned short* __restrict__ h1,
                                                    float* __restrict__ a_src,
                                                    float* __restrict__ a_dst) {
    const int wv = threadIdx.x >> 6;
    const int lane = threadIdx.x & 63;
    const int quad = lane >> 4, c = lane & 15;
    const int base_m = blockIdx.x * 128 + wv * 32;
    bf16x8 af[2][4];
#pragma unroll
    for (int mt = 0; mt < 2; mt++) {
        int row = base_m + mt * 16 + c;
        int rowc = row < N ? row : N - 1;
        const float* ap = x0 + (size_t)rowc * 128 + quad * 8;
#pragma unroll
        for (int ks = 0; ks < 4; ks++) {
            float4 lo = *(const float4*)(ap + ks * 32);
            float4 hi = *(const float4*)(ap + ks * 32 + 4);
            bf16x8 f;
            f[0] = (short)f2b(lo.x); f[1] = (short)f2b(lo.y);
            f[2] = (short)f2b(lo.z); f[3] = (short)f2b(lo.w);
            f[4] = (short)f2b(hi.x); f[5] = (short)f2b(hi.y);
            f[6] = (short)f2b(hi.z); f[7] = (short)f2b(hi.w);
            af[mt][ks] = f;
        }
    }
    // 16 h1 col-tiles + 1 logit tile
    for (int nt = 0; nt < 17; nt++) {
        f32x4 acc0 = {0.f, 0.f, 0.f, 0.f};
        f32x4 acc1 = {0.f, 0.f, 0.f, 0.f};
#pragma unroll
        for (int ks = 0; ks < 4; ks++) {
            bf16x8 bf = *(const bf16x8*)(W1T + (size_t)(nt * 16 + c) * 128 + ks * 32 + quad * 8);
            acc0 = __builtin_amdgcn_mfma_f32_16x16x32_bf16(af[0][ks], bf, acc0, 0, 0, 0);
            acc1 = __builtin_amdgcn_mfma_f32_16x16x32_bf16(af[1][ks], bf, acc1, 0, 0, 0);
        }
        if (nt < 16) {
            const int col = nt * 16 + c;
#pragma unroll
            for (int r = 0; r < 4; r++) {
                int row0 = base_m + quad * 4 + r;
                if (row0 < N) h1[(size_t)row0 * 256 + col] = f2b(acc0[r]);
                int row1 = base_m + 16 + quad * 4 + r;
                if (row1 < N) h1[(size_t)row1 * 256 + col] = f2b(acc1[r]);
            }
        } else {
            // logit tile: col c<8 -> a_src head c; c>=8 -> a_dst head c-8
            float* dst = (c < 8) ? a_src : a_dst;
            int hh = c & 7;
#pragma unroll
            for (int r = 0; r < 4; r++) {
                int row0 = base_m + quad * 4 + r;
                if (row0 < N) dst[(size_t)row0 * 8 + hh] = acc0[r];
                int row1 = base_m + 16 + quad * 4 + r;
                if (row1 < N) dst[(size_t)row1 * 8 + hh] = acc1[r];
            }
        }
    }
}

// ---------------- layer 1 aggregate: one wave per node, fused exp (no max; shift-invariant) ----------------
__global__ __launch_bounds__(256) void seg1_kernel(const int* __restrict__ esrc,
                                                   const int* __restrict__ rofs,
                                                   const float* __restrict__ a_src,
                                                   const float* __restrict__ a_dst,
                                                   const unsigned short* __restrict__ h1,
                                                   const float* __restrict__ b1,
                                                   unsigned short* __restrict__ x2) {
    const int n = (blockIdx.x * 256 + threadIdx.x) >> 6;
    const int lane = threadIdx.x & 63;
    const int h = lane >> 3;
    if (n >= N) return;
    const int rs = rofs[n], re = rofs[n + 1];
    const float ad = a_dst[(size_t)n * 8 + h];
    float d0 = 0.f, d1 = 0.f, d2 = 0.f, d3 = 0.f;
    float4 A0 = {0, 0, 0, 0}, A1 = {0, 0, 0, 0}, A2 = {0, 0, 0, 0}, A3 = {0, 0, 0, 0};
    int j = rs;
    for (; j + 4 <= re; j += 4) {
        int s0 = esrc[j], s1 = esrc[j + 1], s2 = esrc[j + 2], s3 = esrc[j + 3];
        float as0 = a_src[(size_t)s0 * 8 + h];
        float as1 = a_src[(size_t)s1 * 8 + h];
        float as2 = a_src[(size_t)s2 * 8 + h];
        float as3 = a_src[(size_t)s3 * 8 + h];
        ushort4 hb0 = ((const ushort4*)(h1 + (size_t)s0 * 256))[lane];
        ushort4 hb1 = ((const ushort4*)(h1 + (size_t)s1 * 256))[lane];
        ushort4 hb2 = ((const ushort4*)(h1 + (size_t)s2 * 256))[lane];
        ushort4 hb3 = ((const ushort4*)(h1 + (size_t)s3 * 256))[lane];
        float w0 = __expf(lrelu(as0 + ad));
        float w1 = __expf(lrelu(as1 + ad));
        float w2 = __expf(lrelu(as2 + ad));
        float w3 = __expf(lrelu(as3 + ad));
        d0 += w0; d1 += w1; d2 += w2; d3 += w3;
        A0.x += w0 * b2f(hb0.x); A0.y += w0 * b2f(hb0.y); A0.z += w0 * b2f(hb0.z); A0.w += w0 * b2f(hb0.w);
        A1.x += w1 * b2f(hb1.x); A1.y += w1 * b2f(hb1.y); A1.z += w1 * b2f(hb1.z); A1.w += w1 * b2f(hb1.w);
        A2.x += w2 * b2f(hb2.x); A2.y += w2 * b2f(hb2.y); A2.z += w2 * b2f(hb2.z); A2.w += w2 * b2f(hb2.w);
        A3.x += w3 * b2f(hb3.x); A3.y += w3 * b2f(hb3.y); A3.z += w3 * b2f(hb3.z); A3.w += w3 * b2f(hb3.w);
    }
    for (; j < re; j++) {
        int s0 = esrc[j];
        float as0 = a_src[(size_t)s0 * 8 + h];
        ushort4 hb0 = ((const ushort4*)(h1 + (size_t)s0 * 256))[lane];
        float w0 = __expf(lrelu(as0 + ad));
        d0 += w0;
        A0.x += w0 * b2f(hb0.x); A0.y += w0 * b2f(hb0.y); A0.z += w0 * b2f(hb0.z); A0.w += w0 * b2f(hb0.w);
    }
    float den = (d0 + d1) + (d2 + d3);
    float4 acc;
    acc.x = (A0.x + A1.x) + (A2.x + A3.x);
    acc.y = (A0.y + A1.y) + (A2.y + A3.y);
    acc.z = (A0.z + A1.z) + (A2.z + A3.z);
    acc.w = (A0.w + A1.w) + (A2.w + A3.w);
    const float inv = 1.0f / den;
    float4 bb = ((const float4*)b1)[lane];
    float vx = acc.x * inv + bb.x, vy = acc.y * inv + bb.y;
    float vz = acc.z * inv + bb.z, vw = acc.w * inv + bb.w;
    vx = vx > 0.f ? vx : 0.f; vy = vy > 0.f ? vy : 0.f;
    vz = vz > 0.f ? vz : 0.f; vw = vw > 0.f ? vw : 0.f;
    ushort4 o = {f2b(vx), f2b(vy), f2b(vz), f2b(vw)};
    ((ushort4*)(x2 + (size_t)n * 256))[lane] = o;
}

// ---------------- layer 2 GEMM via MFMA: h2 = x2 @ W2 (256->32), fused logits ----------------
__global__ __launch_bounds__(256) void gemm2_kernel(const unsigned short* __restrict__ x2,
                                                    const unsigned short* __restrict__ W2T,
                                                    const float* __restrict__ att_src2,
                                                    const float* __restrict__ att_dst2,
                                                    unsigned short* __restrict__ h2,
                                                    float* __restrict__ a_src2,
                                                    float* __restrict__ a_dst2) {
    const int wv = threadIdx.x >> 6;
    const int lane = threadIdx.x & 63;
    const int quad = lane >> 4, c = lane & 15;
    const int base_m = blockIdx.x * 128 + wv * 32;
    f32x4 acc[2][2] = {{{0, 0, 0, 0}, {0, 0, 0, 0}}, {{0, 0, 0, 0}, {0, 0, 0, 0}}};
#pragma unroll
    for (int ks = 0; ks < 8; ks++) {
        bf16x8 b0 = *(const bf16x8*)(W2T + (size_t)c * 256 + ks * 32 + quad * 8);
        bf16x8 b1 = *(const bf16x8*)(W2T + (size_t)(16 + c) * 256 + ks * 32 + quad * 8);
#pragma unroll
        for (int mt = 0; mt < 2; mt++) {
            int row = base_m + mt * 16 + c;
            int rowc = row < N ? row : N - 1;
            bf16x8 a = *(const bf16x8*)(x2 + (size_t)rowc * 256 + ks * 32 + quad * 8);
            acc[mt][0] = __builtin_amdgcn_mfma_f32_16x16x32_bf16(a, b0, acc[mt][0], 0, 0, 0);
            acc[mt][1] = __builtin_amdgcn_mfma_f32_16x16x32_bf16(a, b1, acc[mt][1], 0, 0, 0);
        }
    }
    float as0 = att_src2[c], as1 = att_src2[16 + c];
    float ad0 = att_dst2[c], ad1 = att_dst2[16 + c];
#pragma unroll
    for (int mt = 0; mt < 2; mt++) {
#pragma unroll
        for (int r = 0; r < 4; r++) {
            int row = base_m + mt * 16 + quad * 4 + r;
            float v0 = acc[mt][0][r], v1 = acc[mt][1][r];
            float ps = v0 * as0 + v1 * as1;
            float pd = v0 * ad0 + v1 * ad1;
#pragma unroll
            for (int off = 1; off < 16; off <<= 1) {
                ps += __shfl_xor(ps, off, 64);
                pd += __shfl_xor(pd, off, 64);
            }
            if (row < N) {
                h2[(size_t)row * 32 + c] = f2b(v0);
                h2[(size_t)row * 32 + 16 + c] = f2b(v1);
                if (c == 0) { a_src2[row] = ps; a_dst2[row] = pd; }
            }
        }
    }
}

// ---------------- layer 2 aggregate: half-wave per node, fused exp ----------------
__global__ __launch_bounds__(256) void seg2_kernel(const int* __restrict__ esrc,
                                                   const int* __restrict__ rofs,
                                                   const float* __restrict__ a_src2,
                                                   const float* __restrict__ a_dst2,
                                                   const unsigned short* __restrict__ h2,
                                                   const float* __restrict__ b2,
                                                   float* __restrict__ v2) {
    const int n = (blockIdx.x * 256 + threadIdx.x) >> 5;
    const int c = threadIdx.x & 31;
    if (n >= N) return;
    const int rs = rofs[n], re = rofs[n + 1];
    const float ad = a_dst2[n];
    float d0 = 0.f, d1 = 0.f, d2 = 0.f, d3 = 0.f;
    float A0 = 0.f, A1 = 0.f, A2 = 0.f, A3 = 0.f;
    int j = rs;
    for (; j + 4 <= re; j += 4) {
        int s0 = esrc[j], s1 = esrc[j + 1], s2 = esrc[j + 2], s3 = esrc[j + 3];
        float as0 = a_src2[s0], as1 = a_src2[s1], as2 = a_src2[s2], as3 = a_src2[s3];
        unsigned short hb0 = h2[(size_t)s0 * 32 + c];
        unsigned short hb1 = h2[(size_t)s1 * 32 + c];
        unsigned short hb2 = h2[(size_t)s2 * 32 + c];
        unsigned short hb3 = h2[(size_t)s3 * 32 + c];
        float w0 = __expf(lrelu(as0 + ad));
        float w1 = __expf(lrelu(as1 + ad));
        float w2 = __expf(lrelu(as2 + ad));
        float w3 = __expf(lrelu(as3 + ad));
        d0 += w0; d1 += w1; d2 += w2; d3 += w3;
        A0 += w0 * b2f(hb0); A1 += w1 * b2f(hb1);
        A2 += w2 * b2f(hb2); A3 += w3 * b2f(hb3);
    }
    for (; j < re; j++) {
        int s0 = esrc[j];
        float w0 = __expf(lrelu(a_src2[s0] + ad));
        d0 += w0;
        A0 += w0 * b2f(h2[(size_t)s0 * 32 + c]);
    }
    float den = (d0 + d1) + (d2 + d3);
    float acc = (A0 + A1) + (A2 + A3);
    v2[(size_t)n * 32 + c] = acc / den + b2[c];
}

// ---------------- final: linear 32->40 ----------------
__global__ __launch_bounds__(256) void final_kernel(const float* __restrict__ v2,
                                                    const float* __restrict__ linW,
                                                    const float* __restrict__ linb,
                                                    float* __restrict__ out) {
    __shared__ float lws[32 * 40];
    __shared__ float vbuf[4][32];
    const int t = threadIdx.x;
    for (int i = t; i < 1280; i += 256) lws[i] = linW[i];
    const int w = t >> 6, lane = t & 63;
    const int n = blockIdx.x * 4 + w;
    if (lane < 32) vbuf[w][lane] = v2[(size_t)n * 32 + lane];
    __syncthreads();
    if (lane < 40) {
        float acc = linb[lane];
#pragma unroll
        for (int c = 0; c < 32; c++) acc += vbuf[w][c] * lws[c * 40 + lane];
        out[(size_t)n * 40 + lane] = acc;
    }
}

extern "C" void kernel_launch(void* const* d_in, const int* in_sizes, int n_in,
                              void* d_out, int out_size, void* d_ws, size_t ws_size,
                              hipStream_t stream) {
    const float* x0       = (const float*)d_in[0];
    const float* W1       = (const float*)d_in[1];
    const float* att_src1 = (const float*)d_in[2];
    const float* att_dst1 = (const float*)d_in[3];
    const float* b1       = (const float*)d_in[4];
    const float* W2       = (const float*)d_in[5];
    const float* att_src2 = (const float*)d_in[6];
    const float* att_dst2 = (const float*)d_in[7];
    const float* b2       = (const float*)d_in[8];
    const float* linW     = (const float*)d_in[9];
    const float* linb     = (const float*)d_in[10];
    const int*   ei       = (const int*)d_in[11];
    float* out = (float*)d_out;
    float* ws  = (float*)d_ws;

    unsigned short* h1  = (unsigned short*)ws;                  // 25.6M bf16
    unsigned short* x2  = (unsigned short*)(ws + 12800000);     // 25.6M bf16
    float* a_src1       = ws + 25600000;                        // 0.8M
    float* a_dst1       = ws + 26400000;                        // 0.8M
    unsigned short* h2  = (unsigned short*)(ws + 27200000);     // 3.2M bf16
    float* v2           = ws + 28800000;                        // 3.2M
    float* a_src2       = ws + 32000000;                        // 0.1M
    float* a_dst2       = ws + 32100000;                        // 0.1M
    unsigned short* W1T = (unsigned short*)(ws + 32200000);     // 272*128 bf16 (incl. fold tile)
    unsigned short* W2T = (unsigned short*)(ws + 32220000);     // 8192 bf16
    int*   hist         = (int*)(ws + 32230000);                // 0.1M
    int*   rofs         = (int*)(ws + 32330000);                // N+1
    int*   cursor       = (int*)(ws + 32440000);                // 0.1M
    int*   bsum         = (int*)(ws + 32540000);                // 512
    int*   esrc         = (int*)(ws + 32541000);                // 1.1M

    hipMemsetAsync(hist, 0, (size_t)N * 4, stream);

    hist_kernel<<<(ETOT + 255) / 256, 256, 0, stream>>>(ei, hist);
    scan1_kernel<<<NB1, 256, 0, stream>>>(hist, rofs, bsum);
    scan2_kernel<<<1, 512, 0, stream>>>(bsum);
    scan3_kernel<<<NB1, 256, 0, stream>>>(rofs, bsum, cursor);
    scatter_kernel<<<(ETOT + 255) / 256, 256, 0, stream>>>(ei, cursor, esrc);

    wt_kernel<<<168, 256, 0, stream>>>(W1, W2, att_src1, att_dst1, W1T, W2T);
    gemm1_kernel<<<(N + 127) / 128, 256, 0, stream>>>(x0, W1T, h1, a_src1, a_dst1);
    seg1_kernel<<<N / 4, 256, 0, stream>>>(esrc, rofs, a_src1, a_dst1, h1, b1, x2);
    gemm2_kernel<<<(N + 127) / 128, 256, 0, stream>>>(x2, W2T, att_src2, att_dst2, h2, a_src2, a_dst2);
    seg2_kernel<<<N / 8, 256, 0, stream>>>(esrc, rofs, a_src2, a_dst2, h2, b2, v2);
    final_kernel<<<N / 4, 256, 0, stream>>>(v2, linW, linb, out);
}